// Round 2
// baseline (82.649 us; speedup 1.0000x reference)
//
#include <hip/hip_runtime.h>

// N = 4096 bodies, 2D. Broad phase keeps first 4N row-major AABB hits,
// exact phase keeps first N true penetrations, resolve is last-write-wins.
#define NB 4096
#define KBROAD (4 * NB)   // 16384
#define KEXACT NB         // 4096
typedef unsigned long long u64;

// ---------------------------------------------------------------------------
// K1: broad-phase counts + per-row hit bitmasks. 4 rows per wave, half the
// j-range per wave (2 waves cover a row group) -> vmem instructions halved
// vs 2-rows/wave while keeping 2 waves/SIMD occupancy.
// AABB test as a single compare: max(|dx|,|dy|) <= r_i + r_j (abs/max are
// VOP3 modifiers). Self-pair exclusion is a wave-uniform scalar bit clear.
// Also inits last_key = -1 and writes per-block 8-row sums for K2's scan.
// Grid: 512 blocks x 256 threads = 2048 waves.
//   block b: rows [8b, 8b+8); wave wv: row group g=wv>>1 (4 rows), half h=wv&1.
// ---------------------------------------------------------------------------
__global__ __launch_bounds__(256) void count_kernel(
    const float2* __restrict__ pos, const float* __restrict__ rad,
    int* __restrict__ row_counts, u64* __restrict__ masks,
    int* __restrict__ blocksum8, int* __restrict__ last_key) {
  __shared__ int ws[4][4];
  int gid = blockIdx.x * blockDim.x + threadIdx.x;
  if (gid < NB) last_key[gid] = -1;
  int t = threadIdx.x;
  int wv = t >> 6, lane = t & 63;
  int g = wv >> 1;                  // row group within block
  int h = wv & 1;                   // j-half
  int r0 = blockIdx.x * 8 + g * 4;  // rows r0..r0+3
  float2 p0 = pos[r0], p1 = pos[r0 + 1], p2 = pos[r0 + 2], p3 = pos[r0 + 3];
  float ra0 = rad[r0], ra1 = rad[r0 + 1], ra2 = rad[r0 + 2], ra3 = rad[r0 + 3];
  int cc = r0 >> 6;                 // chunk holding all 4 self bits
  u64 mw0 = 0, mw1 = 0, mw2 = 0, mw3 = 0;  // lane ci keeps word of chunk h*32+ci
  int c0 = 0, c1 = 0, c2 = 0, c3 = 0;
  #pragma unroll 2
  for (int ci = 0; ci < 32; ++ci) {
    int c = h * 32 + ci;
    int j = c * 64 + lane;
    float2 pj = pos[j];
    float rj = rad[j];
    // |dx|<=rs && |dy|<=rs  ==  max(|dx|,|dy|) <= rs  (finite inputs, exact)
    bool h0 = fmaxf(fabsf(p0.x - pj.x), fabsf(p0.y - pj.y)) <= (ra0 + rj);
    bool h1 = fmaxf(fabsf(p1.x - pj.x), fabsf(p1.y - pj.y)) <= (ra1 + rj);
    bool h2 = fmaxf(fabsf(p2.x - pj.x), fabsf(p2.y - pj.y)) <= (ra2 + rj);
    bool h3 = fmaxf(fabsf(p3.x - pj.x), fabsf(p3.y - pj.y)) <= (ra3 + rj);
    u64 m0 = __ballot(h0);
    u64 m1 = __ballot(h1);
    u64 m2 = __ballot(h2);
    u64 m3 = __ballot(h3);
    if (c == cc) {                  // wave-uniform: drop self-pairs
      m0 &= ~(1ull << (r0 & 63));
      m1 &= ~(1ull << ((r0 + 1) & 63));
      m2 &= ~(1ull << ((r0 + 2) & 63));
      m3 &= ~(1ull << ((r0 + 3) & 63));
    }
    if (lane == ci) { mw0 = m0; mw1 = m1; mw2 = m2; mw3 = m3; }
    c0 += __popcll(m0);
    c1 += __popcll(m1);
    c2 += __popcll(m2);
    c3 += __popcll(m3);
  }
  if (lane < 32) {                  // 32 words per half-row, coalesced 256 B
    size_t base = (size_t)r0 * 64 + h * 32 + lane;
    masks[base] = mw0;
    masks[base + 64] = mw1;
    masks[base + 128] = mw2;
    masks[base + 192] = mw3;
  }
  if (lane == 0) { ws[wv][0] = c0; ws[wv][1] = c1; ws[wv][2] = c2; ws[wv][3] = c3; }
  __syncthreads();
  if (t < 8) {                      // row 8b+4g+k = halves wv=2g and 2g+1
    int gg = t >> 2, k = t & 3;
    row_counts[blockIdx.x * 8 + gg * 4 + k] = ws[2 * gg][k] + ws[2 * gg + 1][k];
  }
  if (t == 0) {
    int s = 0;
    #pragma unroll
    for (int w = 0; w < 4; ++w) s += ws[w][0] + ws[w][1] + ws[w][2] + ws[w][3];
    blocksum8[blockIdx.x] = s;      // 8-row partial for K2's cheap scan
  }
}

// ---------------------------------------------------------------------------
// K2: wave 0 scans the 512 8-row partials (2 KB, not 16 KB) + this block's
// own 16 counts to get row bases; block 0 lane 63 writes the grand total.
// Then fill 4 rows per wave from stored masks (per-lane bit-walk) with the
// exact circle test inline. Penetrating slots get penvec[rank] + packed
// pij[rank] (top nibbles zero -> distinguishable from 0xAA poison).
// Grid: 256 blocks x 256 threads; block b owns rows [16b, 16b+16).
// ---------------------------------------------------------------------------
__global__ __launch_bounds__(256) void fill_kernel(
    const float2* __restrict__ pos, const float* __restrict__ rad,
    const int* __restrict__ row_counts, const int* __restrict__ blocksum8,
    const u64* __restrict__ masks,
    float2* __restrict__ penvec, unsigned* __restrict__ pij,
    int* __restrict__ totalp) {
  __shared__ int rbase[16];
  int t = threadIdx.x;
  int wv = t >> 6, lane = t & 63;
  int b = blockIdx.x;
  if (wv == 0) {
    // lane l owns blocksum8[8l .. 8l+8) as two int4
    const int4* bs4 = (const int4*)blocksum8;
    int4 d0 = bs4[lane * 2];
    int4 d1 = bs4[lane * 2 + 1];
    int s = d0.x + d0.y + d0.z + d0.w + d1.x + d1.y + d1.z + d1.w;
    int v = s;
    #pragma unroll
    for (int off = 1; off < 64; off <<= 1) {
      int u = __shfl_up(v, off);
      if (lane >= off) v += u;
    }
    int excl = v - s;               // sum of partials [0, 8*lane)
    // P = sum blocksum8[0 .. 2b): owner lane L=b>>2, within-lane m=(2b)&7
    int m = (2 * b) & 7;            // uniform, even
    int inner = 0;
    if (m > 0) inner += d0.x + d0.y;
    if (m > 2) inner += d0.z + d0.w;
    if (m > 4) inner += d1.x + d1.y;
    int P = __shfl(excl + inner, b >> 2);
    if (b == 0 && lane == 63) totalp[0] = v;   // grand total (uncapped)
    // own 16 row counts scanned on lanes 0..15
    int cnt = (lane < 16) ? row_counts[16 * b + lane] : 0;
    int vv = cnt;
    #pragma unroll
    for (int off = 1; off < 16; off <<= 1) {
      int u = __shfl_up(vv, off);
      if (lane >= off) vv += u;
    }
    if (lane < 16) rbase[lane] = P + vv - cnt;
  }
  __syncthreads();
  // ---- stage 2: fill 4 rows per wave, lane c owns chunk c of the row.
  for (int q = 0; q < 4; ++q) {
    int r = b * 16 + wv * 4 + q;
    int rowbase = rbase[wv * 4 + q];               // uniform across wave
    if (rowbase >= KBROAD) continue;               // uniform branch
    u64 myw = masks[(size_t)r * 64 + lane];
    int cnt = __popcll(myw);
    int v2 = cnt;
    #pragma unroll
    for (int off = 1; off < 64; off <<= 1) {
      int u = __shfl_up(v2, off);
      if (lane >= off) v2 += u;
    }
    int rank = rowbase + v2 - cnt;                 // base rank of my chunk
    if (!myw) continue;                            // per-lane; no wave ops below
    float2 pr = pos[r];
    float rr = rad[r];
    u64 m = myw;
    while (m && rank < KBROAD) {
      int b2 = __builtin_ctzll(m);
      m &= m - 1;
      int j = (lane << 6) + b2;
      // exact circle test, rn ops to bit-match numpy (no FMA contraction)
      float2 pj = pos[j];
      float dx = pr.x - pj.x, dy = pr.y - pj.y;
      float ss = __fadd_rn(__fadd_rn(__fmul_rn(dx, dx), __fmul_rn(dy, dy)), 1e-12f);
      float dist = __fsqrt_rn(ss);
      float pen = __fsub_rn(__fadd_rn(rr, rad[j]), dist);
      if (pen > 0.0f) {
        float sc = __fdiv_rn(pen, dist);
        penvec[rank] = make_float2(__fmul_rn(dx, sc), __fmul_rn(dy, sc));
        pij[rank] = ((unsigned)r << 16) | (unsigned)j;   // top nibbles 0
      }
      ++rank;
    }
  }
}

// ---------------------------------------------------------------------------
// K3: exact compaction. Hit flag for slot s = (pij[s] valid) && (s < total);
// 0xAA poison can never look valid. Each block redundantly builds the 16384-
// bit hit mask (thread t owns slots t*64..+63), block-scans it, then places
// its 256-slot window (1 slot/thread): ev[rank] + last-writer key atomicMax
// (key = isJ<<16 | rank: j-writes beat i-writes, higher rank wins in-class).
// Grid: 64 blocks x 256 threads.
// ---------------------------------------------------------------------------
__global__ __launch_bounds__(256) void exact_kernel(
    const unsigned* __restrict__ pij, const float2* __restrict__ penvec,
    const int* __restrict__ totalp, float2* __restrict__ ev,
    int* __restrict__ last_key) {
  __shared__ u64 bm[256];
  __shared__ int eb[256];
  __shared__ int wsum[4];
  int t = threadIdx.x;
  int wv = t >> 6, lane = t & 63;
  int total = totalp[0];
  if (total > KBROAD) total = KBROAD;
  u64 m = 0;
  int base = t * 64;
  #pragma unroll
  for (int k = 0; k < 16; ++k) {
    uint4 d = ((const uint4*)pij)[t * 16 + k];
    int s = base + 4 * k;
    unsigned n = 0;
    n |= (((d.x & 0xF000F000u) == 0u) && (s + 0 < total)) ? 1u : 0u;
    n |= (((d.y & 0xF000F000u) == 0u) && (s + 1 < total)) ? 2u : 0u;
    n |= (((d.z & 0xF000F000u) == 0u) && (s + 2 < total)) ? 4u : 0u;
    n |= (((d.w & 0xF000F000u) == 0u) && (s + 3 < total)) ? 8u : 0u;
    m |= (u64)n << (4 * k);
  }
  int cnt = __popcll(m);
  int v = cnt;
  #pragma unroll
  for (int off = 1; off < 64; off <<= 1) {
    int u = __shfl_up(v, off);
    if (lane >= off) v += u;
  }
  if (lane == 63) wsum[wv] = v;
  bm[t] = m;
  __syncthreads();
  int wbase = 0;
  #pragma unroll
  for (int w = 0; w < 4; ++w) if (w < wv) wbase += wsum[w];
  eb[t] = wbase + v - cnt;   // exclusive base of chunk t
  __syncthreads();
  int s = blockIdx.x * 256 + t;
  u64 w = bm[s >> 6];
  if ((w >> (s & 63)) & 1ull) {
    int rank = eb[s >> 6] + __popcll(w & (((u64)1 << (s & 63)) - 1ull));
    if (rank < KEXACT) {
      ev[rank] = penvec[s];
      unsigned p = pij[s];
      atomicMax(&last_key[p >> 16], rank);                 // i-side: key=rank
      atomicMax(&last_key[p & 0xFFFFu], 0x10000 | rank);   // j-side wins
    }
  }
}

// ---------------------------------------------------------------------------
// K4: resolve. key<0 -> untouched; bit16 -> j-side (minus), else i-side.
// Grid: 16 blocks x 256 threads.
// ---------------------------------------------------------------------------
__global__ __launch_bounds__(256) void combine_kernel(
    const float2* __restrict__ pos, const int* __restrict__ last_key,
    const float2* __restrict__ ev, float2* __restrict__ out) {
  int b = blockIdx.x * blockDim.x + threadIdx.x;
  float2 p = pos[b];
  int k = last_key[b];
  float2 o = p;
  if (k >= 0) {
    int rank = k & 0xFFFF;
    float2 e = ev[rank];
    if (k & 0x10000) {
      o.x = __fsub_rn(p.x, __fmul_rn(0.5f, e.x));
      o.y = __fsub_rn(p.y, __fmul_rn(0.5f, e.y));
    } else {
      o.x = __fadd_rn(p.x, __fmul_rn(0.5f, e.x));
      o.y = __fadd_rn(p.y, __fmul_rn(0.5f, e.y));
    }
  }
  out[b] = o;
}

// ---------------------------------------------------------------------------
extern "C" void kernel_launch(void* const* d_in, const int* in_sizes, int n_in,
                              void* d_out, int out_size, void* d_ws, size_t ws_size,
                              hipStream_t stream) {
  const float2* pos = (const float2*)d_in[0];
  const float* rad = (const float*)d_in[1];
  float2* out = (float2*)d_out;

  // Workspace layout (~2.25 MB). pij first for 16B alignment (uint4 reads).
  unsigned* pij = (unsigned*)d_ws;                // KBROAD u32 (64 KB)
  float2* penvec = (float2*)(pij + KBROAD);       // KBROAD float2 (128 KB)
  float2* ev = penvec + KBROAD;                   // KEXACT float2 (32 KB)
  u64* masks = (u64*)(ev + KEXACT);               // NB*64 u64 = 2 MB
  int* row_counts = (int*)(masks + (size_t)NB * 64);  // NB (16 KB)
  int* blocksum8 = row_counts + NB;               // 512 (16B-aligned for int4)
  int* totalp = blocksum8 + 512;                  // 1
  int* last_key = totalp + 1;                     // NB

  count_kernel<<<512, 256, 0, stream>>>(pos, rad, row_counts, masks,
                                        blocksum8, last_key);
  fill_kernel<<<256, 256, 0, stream>>>(pos, rad, row_counts, blocksum8, masks,
                                       penvec, pij, totalp);
  exact_kernel<<<64, 256, 0, stream>>>(pij, penvec, totalp, ev, last_key);
  combine_kernel<<<16, 256, 0, stream>>>(pos, last_key, ev, out);
}

// Round 3
// 81.520 us; speedup vs baseline: 1.0138x; 1.0138x over previous
//
#include <hip/hip_runtime.h>

// N = 4096 bodies, 2D. Broad phase keeps first 4N row-major AABB hits,
// exact phase keeps first N true penetrations, resolve is last-write-wins.
#define NB 4096
#define KBROAD (4 * NB)   // 16384
#define KEXACT NB         // 4096
typedef unsigned long long u64;

// ---------------------------------------------------------------------------
// K1: broad-phase counts + per-row hit bitmasks. 2 rows per wave.
// AABB test as a single compare: max(|dx|,|dy|) <= r_i + r_j (abs/max are
// VOP3 modifiers). Self-pair exclusion done as a wave-uniform scalar bit
// clear on the ballot word (chunk r>>6 only) instead of a per-lane compare.
// Also inits last_key = -1 (consumed by K3/K4; ws is 0xAA-poisoned).
// Grid: 512 blocks x 256 threads = 2048 waves (2 waves/SIMD).
// ---------------------------------------------------------------------------
__global__ __launch_bounds__(256) void count_kernel(
    const float2* __restrict__ pos, const float* __restrict__ rad,
    int* __restrict__ row_counts, u64* __restrict__ masks,
    int* __restrict__ last_key) {
  int gid = blockIdx.x * blockDim.x + threadIdx.x;
  if (gid < NB) last_key[gid] = -1;
  int wave = gid >> 6;
  int lane = gid & 63;
  int r0 = wave * 2;          // rows r0, r0+1
  float2 p0 = pos[r0], p1 = pos[r0 + 1];
  float ra0 = rad[r0], ra1 = rad[r0 + 1];
  int cc = r0 >> 6;           // chunk holding both self bits (r0 even)
  u64 mw0 = 0, mw1 = 0;       // lane c keeps the mask word of chunk c
  int c0 = 0, c1 = 0;
  for (int c = 0; c < 64; ++c) {
    int j = c * 64 + lane;
    float2 pj = pos[j];
    float rj = rad[j];
    // |dx|<=rs && |dy|<=rs  ==  max(|dx|,|dy|) <= rs  (finite inputs, exact)
    bool h0 = fmaxf(fabsf(p0.x - pj.x), fabsf(p0.y - pj.y)) <= (ra0 + rj);
    bool h1 = fmaxf(fabsf(p1.x - pj.x), fabsf(p1.y - pj.y)) <= (ra1 + rj);
    u64 m0 = __ballot(h0);
    u64 m1 = __ballot(h1);
    if (c == cc) {            // wave-uniform: drop self-pairs
      m0 &= ~(1ull << (r0 & 63));
      m1 &= ~(1ull << ((r0 + 1) & 63));
    }
    if (lane == c) { mw0 = m0; mw1 = m1; }
    c0 += __popcll(m0);
    c1 += __popcll(m1);
  }
  masks[(size_t)r0 * 64 + lane] = mw0;          // coalesced 512 B per row
  masks[(size_t)(r0 + 1) * 64 + lane] = mw1;
  if (lane == 0) { row_counts[r0] = c0; row_counts[r0 + 1] = c1; }
}

// ---------------------------------------------------------------------------
// K2: redundant per-block exclusive scan of row counts, then fill this
// block's 16 rows from stored masks (per-lane bit-walk) with the exact
// circle test inline. Penetrating slots get penvec[rank] + packed pij[rank]
// (top nibbles zero -> distinguishable from 0xAA poison = the miss flag).
// Block 0 thread 255 writes the grand total (its scan tail) to totalp.
// Grid: 256 blocks x 256 threads. rb is TRANSPOSED to avoid bank conflicts.
// ---------------------------------------------------------------------------
__global__ __launch_bounds__(256) void fill_kernel(
    const float2* __restrict__ pos, const float* __restrict__ rad,
    const int* __restrict__ row_counts, const u64* __restrict__ masks,
    float2* __restrict__ penvec, unsigned* __restrict__ pij,
    int* __restrict__ totalp) {
  __shared__ int rb[NB];     // transposed row-base table (16 KB)
  __shared__ int wsum[4];
  int t = threadIdx.x;
  int wv = t >> 6, lane = t & 63;
  // ---- stage 1: exclusive scan of 4096 counts (redundant per block).
  // Each thread owns 16 consecutive counts = one 64 B-aligned segment.
  int c[16], s = 0;
  const int4* rc4 = (const int4*)row_counts;
  #pragma unroll
  for (int k4 = 0; k4 < 4; ++k4) {
    int4 d = rc4[t * 4 + k4];
    c[4 * k4 + 0] = d.x; c[4 * k4 + 1] = d.y;
    c[4 * k4 + 2] = d.z; c[4 * k4 + 3] = d.w;
    s += d.x + d.y + d.z + d.w;
  }
  int v = s;  // wave inclusive scan
  #pragma unroll
  for (int off = 1; off < 64; off <<= 1) {
    int u = __shfl_up(v, off);
    if (lane >= off) v += u;
  }
  if (lane == 63) wsum[wv] = v;
  __syncthreads();
  int wbase = 0;
  #pragma unroll
  for (int w = 0; w < 4; ++w) if (w < wv) wbase += wsum[w];
  int run = wbase + v - s;   // exclusive base of thread t's first row
  #pragma unroll
  for (int k = 0; k < 16; ++k) { rb[k * 256 + t] = run; run += c[k]; }
  if (blockIdx.x == 0 && t == 255) totalp[0] = run;   // grand total (uncapped)
  __syncthreads();
  // ---- stage 2: fill 4 rows per wave, lane c owns chunk c of the row.
  for (int q = 0; q < 4; ++q) {
    int r = blockIdx.x * 16 + wv * 4 + q;
    int rowbase = rb[(r & 15) * 256 + (r >> 4)];   // uniform across wave
    if (rowbase >= KBROAD) continue;               // uniform branch
    u64 myw = masks[(size_t)r * 64 + lane];
    int cnt = __popcll(myw);
    int v2 = cnt;
    #pragma unroll
    for (int off = 1; off < 64; off <<= 1) {
      int u = __shfl_up(v2, off);
      if (lane >= off) v2 += u;
    }
    int rank = rowbase + v2 - cnt;                 // base rank of my chunk
    if (!myw) continue;                            // per-lane; no wave ops below
    float2 pr = pos[r];
    float rr = rad[r];
    u64 m = myw;
    while (m && rank < KBROAD) {
      int b = __builtin_ctzll(m);
      m &= m - 1;
      int j = (lane << 6) + b;
      // exact circle test, rn ops to bit-match numpy (no FMA contraction)
      float2 pj = pos[j];
      float dx = pr.x - pj.x, dy = pr.y - pj.y;
      float ss = __fadd_rn(__fadd_rn(__fmul_rn(dx, dx), __fmul_rn(dy, dy)), 1e-12f);
      float dist = __fsqrt_rn(ss);
      float pen = __fsub_rn(__fadd_rn(rr, rad[j]), dist);
      if (pen > 0.0f) {
        float sc = __fdiv_rn(pen, dist);
        penvec[rank] = make_float2(__fmul_rn(dx, sc), __fmul_rn(dy, sc));
        pij[rank] = ((unsigned)r << 16) | (unsigned)j;   // top nibbles 0
      }
      ++rank;
    }
  }
}

// ---------------------------------------------------------------------------
// K3: exact compaction. Hit flag for slot s = (pij[s] valid) && (s < total);
// 0xAA poison can never look valid. Each block redundantly builds the 16384-
// bit hit mask (thread t owns slots t*64..+63), block-scans it, then places
// its 256-slot window (1 slot/thread): ev[rank] + last-writer key atomicMax
// (key = isJ<<16 | rank: j-writes beat i-writes, higher rank wins in-class).
// Grid: 64 blocks x 256 threads.
// ---------------------------------------------------------------------------
__global__ __launch_bounds__(256) void exact_kernel(
    const unsigned* __restrict__ pij, const float2* __restrict__ penvec,
    const int* __restrict__ totalp, float2* __restrict__ ev,
    int* __restrict__ last_key) {
  __shared__ u64 bm[256];
  __shared__ int eb[256];
  __shared__ int wsum[4];
  int t = threadIdx.x;
  int wv = t >> 6, lane = t & 63;
  int total = totalp[0];
  if (total > KBROAD) total = KBROAD;
  u64 m = 0;
  int base = t * 64;
  #pragma unroll
  for (int k = 0; k < 16; ++k) {
    uint4 d = ((const uint4*)pij)[t * 16 + k];
    int s = base + 4 * k;
    unsigned n = 0;
    n |= (((d.x & 0xF000F000u) == 0u) && (s + 0 < total)) ? 1u : 0u;
    n |= (((d.y & 0xF000F000u) == 0u) && (s + 1 < total)) ? 2u : 0u;
    n |= (((d.z & 0xF000F000u) == 0u) && (s + 2 < total)) ? 4u : 0u;
    n |= (((d.w & 0xF000F000u) == 0u) && (s + 3 < total)) ? 8u : 0u;
    m |= (u64)n << (4 * k);
  }
  int cnt = __popcll(m);
  int v = cnt;
  #pragma unroll
  for (int off = 1; off < 64; off <<= 1) {
    int u = __shfl_up(v, off);
    if (lane >= off) v += u;
  }
  if (lane == 63) wsum[wv] = v;
  bm[t] = m;
  __syncthreads();
  int wbase = 0;
  #pragma unroll
  for (int w = 0; w < 4; ++w) if (w < wv) wbase += wsum[w];
  eb[t] = wbase + v - cnt;   // exclusive base of chunk t
  __syncthreads();
  int s = blockIdx.x * 256 + t;
  u64 w = bm[s >> 6];
  if ((w >> (s & 63)) & 1ull) {
    int rank = eb[s >> 6] + __popcll(w & (((u64)1 << (s & 63)) - 1ull));
    if (rank < KEXACT) {
      ev[rank] = penvec[s];
      unsigned p = pij[s];
      atomicMax(&last_key[p >> 16], rank);                 // i-side: key=rank
      atomicMax(&last_key[p & 0xFFFFu], 0x10000 | rank);   // j-side wins
    }
  }
}

// ---------------------------------------------------------------------------
// K4: resolve. key<0 -> untouched; bit16 -> j-side (minus), else i-side.
// Grid: 16 blocks x 256 threads.
// ---------------------------------------------------------------------------
__global__ __launch_bounds__(256) void combine_kernel(
    const float2* __restrict__ pos, const int* __restrict__ last_key,
    const float2* __restrict__ ev, float2* __restrict__ out) {
  int b = blockIdx.x * blockDim.x + threadIdx.x;
  float2 p = pos[b];
  int k = last_key[b];
  float2 o = p;
  if (k >= 0) {
    int rank = k & 0xFFFF;
    float2 e = ev[rank];
    if (k & 0x10000) {
      o.x = __fsub_rn(p.x, __fmul_rn(0.5f, e.x));
      o.y = __fsub_rn(p.y, __fmul_rn(0.5f, e.y));
    } else {
      o.x = __fadd_rn(p.x, __fmul_rn(0.5f, e.x));
      o.y = __fadd_rn(p.y, __fmul_rn(0.5f, e.y));
    }
  }
  out[b] = o;
}

// ---------------------------------------------------------------------------
extern "C" void kernel_launch(void* const* d_in, const int* in_sizes, int n_in,
                              void* d_out, int out_size, void* d_ws, size_t ws_size,
                              hipStream_t stream) {
  const float2* pos = (const float2*)d_in[0];
  const float* rad = (const float*)d_in[1];
  float2* out = (float2*)d_out;

  // Workspace layout (~2.25 MB). pij first for 16B alignment (uint4 reads).
  unsigned* pij = (unsigned*)d_ws;                // KBROAD u32 (64 KB)
  float2* penvec = (float2*)(pij + KBROAD);       // KBROAD float2 (128 KB)
  float2* ev = penvec + KBROAD;                   // KEXACT float2 (32 KB)
  u64* masks = (u64*)(ev + KEXACT);               // NB*64 u64 = 2 MB
  int* row_counts = (int*)(masks + (size_t)NB * 64);  // NB
  int* totalp = row_counts + NB;                  // 1
  int* last_key = totalp + 1;                     // NB

  count_kernel<<<512, 256, 0, stream>>>(pos, rad, row_counts, masks, last_key);
  fill_kernel<<<256, 256, 0, stream>>>(pos, rad, row_counts, masks, penvec,
                                       pij, totalp);
  exact_kernel<<<64, 256, 0, stream>>>(pij, penvec, totalp, ev, last_key);
  combine_kernel<<<16, 256, 0, stream>>>(pos, last_key, ev, out);
}